// Round 1
// baseline (633.388 us; speedup 1.0000x reference)
//
#include <hip/hip_runtime.h>
#include <hip/hip_bf16.h>

// Deter GRU cell: B=1024, DETER=4096, STOCH=1024, ACT=128, HID=1024, BLOCKS=8, dpb=512
// Pipeline:
//   act_n = action / max(|action|,1)
//   pre[:, :3072] = {deter@w0+b0 | stoch@w1+b1 | act_n@w2+b2}
//   x = silu(rmsnorm(pre_branch))                     [1024,3072]
//   pre = blockcat(deter_g, x) @ hw0 + hb0            [1024,4096]
//   h = silu(rmsnorm(pre, hg0))
//   pre = blockdiag(h) @ hw1 + hb1 ; h = silu(rmsnorm(pre, hg1))
//   pre = blockdiag(h) @ gw + gb                      [1024,12288]
//   out = GRU(pre, deter)

typedef __attribute__((ext_vector_type(8))) __bf16 bf16x8;
typedef __attribute__((ext_vector_type(4))) float f32x4;

__device__ __forceinline__ short f2bf(float f) {
    union { float f; unsigned u; } a; a.f = f;
    unsigned r = a.u + 0x7FFFu + ((a.u >> 16) & 1u);
    return (short)(r >> 16);
}

// Generic block GEMM: C[m, g*Nb+n] = sum_k Asrc[m,k] * W[g][k][n] + bias[g*Nb+n]
// Asrc: k < K1 -> A1[m, a1_goff*g + k] (lda1); else A2[m, k-K1] (lda2)
// Requires: K1 % 32 == 0, (K1+K2) % 32 == 0, M % 128 == 0, Nb % 128 == 0.
__global__ __launch_bounds__(256) void gemm_mfma(
    const float* __restrict__ A1, int lda1, int a1_goff, int K1,
    const float* __restrict__ A2, int lda2, int K2,
    const float* __restrict__ W, const float* __restrict__ bias,
    float* __restrict__ C, int ldc, int Nb)
{
    __shared__ short As[128][40];   // [m][k], pad 32->40 (80B rows, 16B-aligned)
    __shared__ short Bs[128][40];   // [n][k] transposed

    const int g  = blockIdx.z;
    const int n0 = blockIdx.x << 7;
    const int m0 = blockIdx.y << 7;
    const int Ktot = K1 + K2;
    const float* Wg = W + (size_t)g * Ktot * Nb;
    const int a1c = a1_goff * g;

    const int t = threadIdx.x;
    const int lane = t & 63;
    const int wv = t >> 6;
    const int wr = (wv >> 1) << 6;   // wave row offset in tile
    const int wc = (wv & 1) << 6;    // wave col offset
    const int lr = lane & 15;
    const int lk = (lane >> 4) << 3;

    f32x4 acc[4][4];
    #pragma unroll
    for (int i = 0; i < 4; ++i)
        #pragma unroll
        for (int j = 0; j < 4; ++j)
            acc[i][j] = (f32x4){0.f, 0.f, 0.f, 0.f};

    const int ar = t >> 3;          // A stage: row 0..31 (+32*q)
    const int ak = (t & 7) << 2;    // A stage: k 0,4..28
    const int bn = t & 127;         // B stage: col
    const int kh = (t >> 7) << 4;   // B stage: k half (0 or 16)

    for (int k0 = 0; k0 < Ktot; k0 += 32) {
        const float* sA; int lda; int colb;
        if (k0 < K1) { sA = A1; lda = lda1; colb = a1c + k0; }
        else         { sA = A2; lda = lda2; colb = k0 - K1; }

        const float* ap = sA + (size_t)(m0 + ar) * lda + colb + ak;
        #pragma unroll
        for (int q = 0; q < 4; ++q) {
            float4 v = *(const float4*)(ap + (size_t)(q * 32) * lda);
            short4 h;
            h.x = f2bf(v.x); h.y = f2bf(v.y); h.z = f2bf(v.z); h.w = f2bf(v.w);
            *(short4*)&As[ar + q * 32][ak] = h;
        }

        const float* bp = Wg + (size_t)(k0 + kh) * Nb + n0 + bn;
        short vb[16];
        #pragma unroll
        for (int j = 0; j < 16; ++j) vb[j] = f2bf(bp[(size_t)j * Nb]);
        #pragma unroll
        for (int j = 0; j < 4; ++j)
            *(short4*)&Bs[bn][kh + j * 4] = *(short4*)&vb[j * 4];

        __syncthreads();

        bf16x8 af[4], bfr[4];
        #pragma unroll
        for (int i = 0; i < 4; ++i) af[i]  = *(const bf16x8*)&As[wr + i * 16 + lr][lk];
        #pragma unroll
        for (int j = 0; j < 4; ++j) bfr[j] = *(const bf16x8*)&Bs[wc + j * 16 + lr][lk];

        #pragma unroll
        for (int i = 0; i < 4; ++i)
            #pragma unroll
            for (int j = 0; j < 4; ++j)
                acc[i][j] = __builtin_amdgcn_mfma_f32_16x16x32_bf16(af[i], bfr[j], acc[i][j], 0, 0, 0);

        __syncthreads();
    }

    const int cr = (lane >> 4) << 2;
    #pragma unroll
    for (int i = 0; i < 4; ++i) {
        int row = m0 + wr + i * 16 + cr;
        #pragma unroll
        for (int j = 0; j < 4; ++j) {
            int colg = g * Nb + n0 + wc + j * 16 + (lane & 15);
            float bv = bias[colg];
            float* cp = C + (size_t)row * ldc + colg;
            #pragma unroll
            for (int r = 0; r < 4; ++r)
                cp[(size_t)r * ldc] = acc[i][j][r] + bv;
        }
    }
}

// Per-row RMSNorm(+gain) then SiLU. grid = (rows, nseg); segment br covers cols [br*D, (br+1)*D)
__global__ __launch_bounds__(256) void rmsnorm_silu_k(
    const float* __restrict__ in, int ldin,
    const float* __restrict__ g0, const float* __restrict__ g1, const float* __restrict__ g2,
    float* __restrict__ out, int ldout, int D)
{
    const int row = blockIdx.x;
    const int br = blockIdx.y;
    const float* gain = (br == 0) ? g0 : (br == 1) ? g1 : g2;
    const float* ip = in + (size_t)row * ldin + (size_t)br * D;
    float* op = out + (size_t)row * ldout + (size_t)br * D;
    const int t = threadIdx.x;

    float ss = 0.f;
    for (int i = t * 4; i < D; i += 1024) {
        float4 v = *(const float4*)(ip + i);
        ss += v.x * v.x + v.y * v.y + v.z * v.z + v.w * v.w;
    }
    #pragma unroll
    for (int o = 32; o > 0; o >>= 1) ss += __shfl_down(ss, o, 64);
    __shared__ float sred[4];
    if ((t & 63) == 0) sred[t >> 6] = ss;
    __syncthreads();
    float tot = sred[0] + sred[1] + sred[2] + sred[3];
    float scale = rsqrtf(tot / (float)D + 1e-4f);

    for (int i = t * 4; i < D; i += 1024) {
        float4 v = *(const float4*)(ip + i);
        float4 gv = *(const float4*)(gain + i);
        float4 o4; float y;
        y = v.x * scale * gv.x; o4.x = y / (1.f + __expf(-y));
        y = v.y * scale * gv.y; o4.y = y / (1.f + __expf(-y));
        y = v.z * scale * gv.z; o4.z = y / (1.f + __expf(-y));
        y = v.w * scale * gv.w; o4.w = y / (1.f + __expf(-y));
        *(float4*)(op + i) = o4;
    }
}

__global__ __launch_bounds__(256) void act_prep(const float* __restrict__ a,
                                                float* __restrict__ o, int n)
{
    int i = (blockIdx.x * 256 + threadIdx.x) * 4;
    if (i < n) {
        float4 v = *(const float4*)(a + i);
        float4 r;
        r.x = v.x / fmaxf(fabsf(v.x), 1.f);
        r.y = v.y / fmaxf(fabsf(v.y), 1.f);
        r.z = v.z / fmaxf(fabsf(v.z), 1.f);
        r.w = v.w / fmaxf(fabsf(v.w), 1.f);
        *(float4*)(o + i) = r;
    }
}

__device__ __forceinline__ float gru1(float r, float cc, float u, float d) {
    float reset = 1.f / (1.f + __expf(-r));
    float cand = tanhf(reset * cc);
    float upd = 1.f / (1.f + __expf(-(u - 1.f)));
    return upd * cand + (1.f - upd) * d;
}

__global__ __launch_bounds__(256) void gru_k(const float* __restrict__ pre,
                                             const float* __restrict__ deter,
                                             float* __restrict__ out)
{
    int idx = (blockIdx.x * 256 + threadIdx.x) * 4;  // over 1024*4096
    int b = idx >> 12;
    int c = idx & 4095;
    int g = c >> 9, ii = c & 511;
    const float* p = pre + (size_t)b * 12288 + g * 1536 + ii;
    float4 pr = *(const float4*)p;
    float4 pc = *(const float4*)(p + 512);
    float4 pu = *(const float4*)(p + 1024);
    float4 dv = *(const float4*)(deter + idx);
    float4 o4;
    o4.x = gru1(pr.x, pc.x, pu.x, dv.x);
    o4.y = gru1(pr.y, pc.y, pu.y, dv.y);
    o4.z = gru1(pr.z, pc.z, pu.z, dv.z);
    o4.w = gru1(pr.w, pc.w, pu.w, dv.w);
    *(float4*)(out + idx) = o4;
}

extern "C" void kernel_launch(void* const* d_in, const int* in_sizes, int n_in,
                              void* d_out, int out_size, void* d_ws, size_t ws_size,
                              hipStream_t stream)
{
    (void)in_sizes; (void)n_in; (void)out_size; (void)ws_size;
    const float* stoch  = (const float*)d_in[0];
    const float* deter  = (const float*)d_in[1];
    const float* action = (const float*)d_in[2];
    const float* w0 = (const float*)d_in[3];
    const float* b0 = (const float*)d_in[4];
    const float* g0 = (const float*)d_in[5];
    const float* w1 = (const float*)d_in[6];
    const float* b1 = (const float*)d_in[7];
    const float* g1 = (const float*)d_in[8];
    const float* w2 = (const float*)d_in[9];
    const float* b2 = (const float*)d_in[10];
    const float* g2 = (const float*)d_in[11];
    const float* hw0 = (const float*)d_in[12];
    const float* hb0 = (const float*)d_in[13];
    const float* hg0 = (const float*)d_in[14];
    const float* hw1 = (const float*)d_in[15];
    const float* hb1 = (const float*)d_in[16];
    const float* hg1 = (const float*)d_in[17];
    const float* gw  = (const float*)d_in[18];
    const float* gb  = (const float*)d_in[19];
    float* out = (float*)d_out;

    float* act_n = (float*)d_ws;                 // 131072
    float* xbuf  = act_n + 131072;               // 1024*3072
    float* hbuf  = xbuf + (size_t)1024 * 3072;   // 1024*4096
    float* pre   = hbuf + (size_t)1024 * 4096;   // 1024*12288

    dim3 blk(256);

    act_prep<<<128, blk, 0, stream>>>(action, act_n, 131072);

    // input branches -> pre[:, :3072]
    gemm_mfma<<<dim3(8, 8, 1), blk, 0, stream>>>(deter, 4096, 0, 4096, nullptr, 0, 0,
                                                 w0, b0, pre + 0, 3072, 1024);
    gemm_mfma<<<dim3(8, 8, 1), blk, 0, stream>>>(stoch, 1024, 0, 1024, nullptr, 0, 0,
                                                 w1, b1, pre + 1024, 3072, 1024);
    gemm_mfma<<<dim3(8, 8, 1), blk, 0, stream>>>(act_n, 128, 0, 128, nullptr, 0, 0,
                                                 w2, b2, pre + 2048, 3072, 1024);
    rmsnorm_silu_k<<<dim3(1024, 3), blk, 0, stream>>>(pre, 3072, g0, g1, g2, xbuf, 3072, 1024);

    // hidden block layer 0: A = [deter_g | x], K = 512 + 3072
    gemm_mfma<<<dim3(4, 8, 8), blk, 0, stream>>>(deter, 4096, 512, 512, xbuf, 3072, 3072,
                                                 hw0, hb0, pre, 4096, 512);
    rmsnorm_silu_k<<<dim3(1024, 1), blk, 0, stream>>>(pre, 4096, hg0, hg0, hg0, hbuf, 4096, 4096);

    // hidden block layer 1: block-diagonal K=512
    gemm_mfma<<<dim3(4, 8, 8), blk, 0, stream>>>(hbuf, 4096, 512, 512, nullptr, 0, 0,
                                                 hw1, hb1, pre, 4096, 512);
    rmsnorm_silu_k<<<dim3(1024, 1), blk, 0, stream>>>(pre, 4096, hg1, hg1, hg1, hbuf, 4096, 4096);

    // gate: block-diagonal K=512 -> [1024, 12288]
    gemm_mfma<<<dim3(12, 8, 8), blk, 0, stream>>>(hbuf, 4096, 512, 512, nullptr, 0, 0,
                                                  gw, gb, pre, 12288, 1536);

    gru_k<<<4096, blk, 0, stream>>>(pre, deter, out);
}

// Round 2
// 418.577 us; speedup vs baseline: 1.5132x; 1.5132x over previous
//
#include <hip/hip_runtime.h>
#include <hip/hip_bf16.h>

// Deter GRU cell: B=1024, DETER=4096, STOCH=1024, ACT=128, HID=1024, BLOCKS=8, dpb=512
//
// Structure: 6 GEMMs (bf16 MFMA, f32 accum) + RMSNorm/SiLU glue + GRU epilogue.
// Split-K partials (latency hiding for big-K GEMMs); reduction fused into the
// RMSNorm consumer. Double-buffered LDS, one barrier per K-step, packed
// f32->bf16 conversion (v_cvt_pk_bf16_f32 via __float22bfloat162_rn).

typedef __attribute__((ext_vector_type(8))) __bf16 bf16x8;
typedef __attribute__((ext_vector_type(4))) float f32x4;

__device__ __forceinline__ unsigned pack_bf2(float a, float b) {
    __hip_bfloat162 h = __float22bfloat162_rn(make_float2(a, b));
    union { __hip_bfloat162 h; unsigned u; } c; c.h = h;
    return c.u;
}

// Block GEMM with split-K partials.
// C_s[m, g*Nb+n] = sum_{k in chunk s} Asrc[m,k] * W[g][k][n]  (+bias if s==0)
// Asrc: k < K1 -> A1[m, a1_goff*g + k] (lda1); else A2[m, k-K1] (lda2)
// z = g*nSplit + s. Kchunk % 32 == 0. Tile 128x128, BK=32, 4 waves.
__global__ __launch_bounds__(256) void gemm_mfma(
    const float* __restrict__ A1, int lda1, int a1_goff, int K1,
    const float* __restrict__ A2, int lda2, int K2,
    const float* __restrict__ W, const float* __restrict__ bias,
    float* __restrict__ C, int ldc, int Nb,
    int nSplit, int Kchunk, size_t pstride)
{
    __shared__ short As[2][128][40];   // [buf][m][k] bf16, pad 32->40
    __shared__ short Bs[2][128][40];   // [buf][n][k] transposed

    const int z = blockIdx.z;
    const int g = z / nSplit;
    const int s = z % nSplit;
    const int n0 = blockIdx.x << 7;
    const int m0 = blockIdx.y << 7;
    const int Ktot = K1 + K2;
    const int kbeg = s * Kchunk;
    const float* Wg = W + (size_t)g * Ktot * Nb;
    const int a1c = a1_goff * g;
    float* Cs = C + (size_t)s * pstride;

    const int t = threadIdx.x;
    const int lane = t & 63;
    const int wv = t >> 6;
    const int wr = (wv >> 1) << 6;   // wave row offset in tile
    const int wc = (wv & 1) << 6;    // wave col offset
    const int lr = lane & 15;
    const int lk = (lane >> 4) << 3;

    // A-stage: 4 passes of 32 rows x 32 cols (float4 per thread)
    const int ar = t >> 3;           // 0..31
    const int ak = (t & 7) << 2;     // 0,4..28
    // B-stage: thread micro-tile 4k x 4n
    const int bkq = (t >> 5) << 2;   // 0,4..28
    const int bn  = (t & 31) << 2;   // 0..124

    f32x4 acc[4][4];
    #pragma unroll
    for (int i = 0; i < 4; ++i)
        #pragma unroll
        for (int j = 0; j < 4; ++j)
            acc[i][j] = (f32x4){0.f, 0.f, 0.f, 0.f};

    auto stage = [&](int k0, int buf) {
        const float* sA; int lda; int colb;
        if (k0 < K1) { sA = A1; lda = lda1; colb = a1c + k0; }
        else         { sA = A2; lda = lda2; colb = k0 - K1; }
        const float* ap = sA + (size_t)(m0 + ar) * lda + colb + ak;
        float4 va[4];
        #pragma unroll
        for (int q = 0; q < 4; ++q)
            va[q] = *(const float4*)(ap + (size_t)(q * 32) * lda);
        const float* bp = Wg + (size_t)k0 * Nb + n0 + bn;
        float4 vb[4];
        #pragma unroll
        for (int i = 0; i < 4; ++i)
            vb[i] = *(const float4*)(bp + (size_t)(bkq + i) * Nb);
        #pragma unroll
        for (int q = 0; q < 4; ++q) {
            uint2 u;
            u.x = pack_bf2(va[q].x, va[q].y);
            u.y = pack_bf2(va[q].z, va[q].w);
            *(uint2*)&As[buf][ar + q * 32][ak] = u;
        }
        const float* vbf = (const float*)vb;   // vb[i] component j = vbf[i*4+j]
        #pragma unroll
        for (int j = 0; j < 4; ++j) {
            uint2 u;
            u.x = pack_bf2(vbf[0 * 4 + j], vbf[1 * 4 + j]);
            u.y = pack_bf2(vbf[2 * 4 + j], vbf[3 * 4 + j]);
            *(uint2*)&Bs[buf][bn + j][bkq] = u;
        }
    };

    const int nt = Kchunk >> 5;
    stage(kbeg, 0);

    for (int it = 0; it < nt; ++it) {
        const int buf = it & 1;
        __syncthreads();
        if (it + 1 < nt) stage(kbeg + ((it + 1) << 5), buf ^ 1);

        bf16x8 af[4], bfr[4];
        #pragma unroll
        for (int i = 0; i < 4; ++i) af[i]  = *(const bf16x8*)&As[buf][wr + i * 16 + lr][lk];
        #pragma unroll
        for (int j = 0; j < 4; ++j) bfr[j] = *(const bf16x8*)&Bs[buf][wc + j * 16 + lr][lk];
        #pragma unroll
        for (int i = 0; i < 4; ++i)
            #pragma unroll
            for (int j = 0; j < 4; ++j)
                acc[i][j] = __builtin_amdgcn_mfma_f32_16x16x32_bf16(af[i], bfr[j], acc[i][j], 0, 0, 0);
    }

    const int cr = (lane >> 4) << 2;
    #pragma unroll
    for (int i = 0; i < 4; ++i) {
        int row = m0 + wr + i * 16 + cr;
        #pragma unroll
        for (int j = 0; j < 4; ++j) {
            int colg = g * Nb + n0 + wc + j * 16 + (lane & 15);
            float bv = (s == 0) ? bias[colg] : 0.f;
            float* cp = Cs + (size_t)row * ldc + colg;
            #pragma unroll
            for (int r = 0; r < 4; ++r)
                cp[(size_t)r * ldc] = acc[i][j][r] + bv;
        }
    }
}

// Sum S split-K partials, RMSNorm(+gain), SiLU. grid = (rows, nseg).
// Row cached in registers between the two passes. D in {1024, 4096}.
__global__ __launch_bounds__(256) void rmsnorm_silu_k(
    const float* __restrict__ in, int ldin, size_t pstride, int S,
    const float* __restrict__ g0, const float* __restrict__ g1, const float* __restrict__ g2,
    float* __restrict__ out, int ldout, int D)
{
    const int row = blockIdx.x;
    const int br = blockIdx.y;
    const float* gain = (br == 0) ? g0 : (br == 1) ? g1 : g2;
    const float* ip = in + (size_t)row * ldin + (size_t)br * D;
    float* op = out + (size_t)row * ldout + (size_t)br * D;
    const int t = threadIdx.x;
    const int nc = D >> 10;

    float4 cache[4];
    float ss = 0.f;
    #pragma unroll
    for (int c = 0; c < 4; ++c) {
        if (c < nc) {
            int i = c * 1024 + t * 4;
            float4 v = *(const float4*)(ip + i);
            for (int s2 = 1; s2 < S; ++s2) {
                float4 w = *(const float4*)(ip + (size_t)s2 * pstride + i);
                v.x += w.x; v.y += w.y; v.z += w.z; v.w += w.w;
            }
            cache[c] = v;
            ss += v.x * v.x + v.y * v.y + v.z * v.z + v.w * v.w;
        }
    }

    #pragma unroll
    for (int o = 32; o > 0; o >>= 1) ss += __shfl_down(ss, o, 64);
    __shared__ float sred[4];
    if ((t & 63) == 0) sred[t >> 6] = ss;
    __syncthreads();
    float tot = sred[0] + sred[1] + sred[2] + sred[3];
    float scale = rsqrtf(tot / (float)D + 1e-4f);

    #pragma unroll
    for (int c = 0; c < 4; ++c) {
        if (c < nc) {
            int i = c * 1024 + t * 4;
            float4 v = cache[c];
            float4 gv = *(const float4*)(gain + i);
            float4 o4; float y;
            y = v.x * scale * gv.x; o4.x = y / (1.f + __expf(-y));
            y = v.y * scale * gv.y; o4.y = y / (1.f + __expf(-y));
            y = v.z * scale * gv.z; o4.z = y / (1.f + __expf(-y));
            y = v.w * scale * gv.w; o4.w = y / (1.f + __expf(-y));
            *(float4*)(op + i) = o4;
        }
    }
}

__global__ __launch_bounds__(256) void act_prep(const float* __restrict__ a,
                                                float* __restrict__ o, int n)
{
    int i = (blockIdx.x * 256 + threadIdx.x) * 4;
    if (i < n) {
        float4 v = *(const float4*)(a + i);
        float4 r;
        r.x = v.x / fmaxf(fabsf(v.x), 1.f);
        r.y = v.y / fmaxf(fabsf(v.y), 1.f);
        r.z = v.z / fmaxf(fabsf(v.z), 1.f);
        r.w = v.w / fmaxf(fabsf(v.w), 1.f);
        *(float4*)(o + i) = r;
    }
}

__device__ __forceinline__ float gru1(float r, float cc, float u, float d) {
    float reset = 1.f / (1.f + __expf(-r));
    float cand = tanhf(reset * cc);
    float upd = 1.f / (1.f + __expf(-(u - 1.f)));
    return upd * cand + (1.f - upd) * d;
}

__global__ __launch_bounds__(256) void gru_k(const float* __restrict__ pre,
                                             const float* __restrict__ deter,
                                             float* __restrict__ out)
{
    int idx = (blockIdx.x * 256 + threadIdx.x) * 4;  // over 1024*4096
    int b = idx >> 12;
    int c = idx & 4095;
    int g = c >> 9, ii = c & 511;
    const float* p = pre + (size_t)b * 12288 + g * 1536 + ii;
    float4 pr = *(const float4*)p;
    float4 pc = *(const float4*)(p + 512);
    float4 pu = *(const float4*)(p + 1024);
    float4 dv = *(const float4*)(deter + idx);
    float4 o4;
    o4.x = gru1(pr.x, pc.x, pu.x, dv.x);
    o4.y = gru1(pr.y, pc.y, pu.y, dv.y);
    o4.z = gru1(pr.z, pc.z, pu.z, dv.z);
    o4.w = gru1(pr.w, pc.w, pu.w, dv.w);
    *(float4*)(out + idx) = o4;
}

extern "C" void kernel_launch(void* const* d_in, const int* in_sizes, int n_in,
                              void* d_out, int out_size, void* d_ws, size_t ws_size,
                              hipStream_t stream)
{
    (void)in_sizes; (void)n_in; (void)out_size; (void)ws_size;
    const float* stoch  = (const float*)d_in[0];
    const float* deter  = (const float*)d_in[1];
    const float* action = (const float*)d_in[2];
    const float* w0 = (const float*)d_in[3];
    const float* b0 = (const float*)d_in[4];
    const float* g0 = (const float*)d_in[5];
    const float* w1 = (const float*)d_in[6];
    const float* b1 = (const float*)d_in[7];
    const float* g1 = (const float*)d_in[8];
    const float* w2 = (const float*)d_in[9];
    const float* b2 = (const float*)d_in[10];
    const float* g2 = (const float*)d_in[11];
    const float* hw0 = (const float*)d_in[12];
    const float* hb0 = (const float*)d_in[13];
    const float* hg0 = (const float*)d_in[14];
    const float* hw1 = (const float*)d_in[15];
    const float* hb1 = (const float*)d_in[16];
    const float* hg1 = (const float*)d_in[17];
    const float* gw  = (const float*)d_in[18];
    const float* gb  = (const float*)d_in[19];
    float* out = (float*)d_out;

    // workspace layout (floats): total 20,054,016 (~80.2 MB)
    float* act_n = (float*)d_ws;                       // 131072
    float* xbuf  = act_n + 131072;                     // 1024*3072
    float* hbuf  = xbuf + (size_t)1024 * 3072;         // 1024*4096
    float* part  = hbuf + (size_t)1024 * 4096;         // 12,582,912 (partials / gate pre)

    const size_t PS_BR = (size_t)1024 * 3072;          // branch partial stride
    const size_t PS_H  = (size_t)1024 * 4096;          // hidden partial stride

    dim3 blk(256);

    act_prep<<<128, blk, 0, stream>>>(action, act_n, 131072);

    // input branches -> part[s][:, seg], split-K S=4
    gemm_mfma<<<dim3(8, 8, 4), blk, 0, stream>>>(deter, 4096, 0, 4096, nullptr, 0, 0,
                                                 w0, b0, part + 0, 3072, 1024, 4, 1024, PS_BR);
    gemm_mfma<<<dim3(8, 8, 4), blk, 0, stream>>>(stoch, 1024, 0, 1024, nullptr, 0, 0,
                                                 w1, b1, part + 1024, 3072, 1024, 4, 256, PS_BR);
    gemm_mfma<<<dim3(8, 8, 4), blk, 0, stream>>>(act_n, 128, 0, 128, nullptr, 0, 0,
                                                 w2, b2, part + 2048, 3072, 1024, 4, 32, PS_BR);
    rmsnorm_silu_k<<<dim3(1024, 3), blk, 0, stream>>>(part, 3072, PS_BR, 4,
                                                      g0, g1, g2, xbuf, 3072, 1024);

    // hidden block layer 0: A = [deter_g | x], K = 512 + 3072, S=2
    gemm_mfma<<<dim3(4, 8, 16), blk, 0, stream>>>(deter, 4096, 512, 512, xbuf, 3072, 3072,
                                                  hw0, hb0, part, 4096, 512, 2, 1792, PS_H);
    rmsnorm_silu_k<<<dim3(1024, 1), blk, 0, stream>>>(part, 4096, PS_H, 2,
                                                      hg0, hg0, hg0, hbuf, 4096, 4096);

    // hidden block layer 1: block-diagonal K=512, S=2
    gemm_mfma<<<dim3(4, 8, 16), blk, 0, stream>>>(hbuf, 4096, 512, 512, nullptr, 0, 0,
                                                  hw1, hb1, part, 4096, 512, 2, 256, PS_H);
    rmsnorm_silu_k<<<dim3(1024, 1), blk, 0, stream>>>(part, 4096, PS_H, 2,
                                                      hg1, hg1, hg1, hbuf, 4096, 4096);

    // gate: block-diagonal K=512 -> [1024, 12288], no split
    gemm_mfma<<<dim3(12, 8, 8), blk, 0, stream>>>(hbuf, 4096, 512, 512, nullptr, 0, 0,
                                                  gw, gb, part, 12288, 1536, 1, 512, 0);

    gru_k<<<4096, blk, 0, stream>>>(part, deter, out);
}

// Round 3
// 377.403 us; speedup vs baseline: 1.6783x; 1.1091x over previous
//
#include <hip/hip_runtime.h>
#include <hip/hip_bf16.h>

// Deter GRU cell on MI355X. All GEMMs run bf16 MFMA with global_load_lds
// staging from pre-converted bf16 operands (weights transposed to [N][K] once
// per call). f32 accumulation; norms/GRU glue fused where cheap.

typedef unsigned short u16;
typedef unsigned int u32;
typedef __attribute__((ext_vector_type(8))) __bf16 bf16x8;
typedef __attribute__((ext_vector_type(4))) float f32x4;

#define AS3 __attribute__((address_space(3)))
#define AS1 __attribute__((address_space(1)))

__device__ __forceinline__ u16 f2bf(float f) {
    union { float f; u32 u; } a; a.f = f;
    u32 r = a.u + 0x7FFFu + ((a.u >> 16) & 1u);
    return (u16)(r >> 16);
}
__device__ __forceinline__ float bf2f(u16 h) {
    union { u32 u; float f; } c; c.u = ((u32)h) << 16; return c.f;
}
__device__ __forceinline__ u32 pk2(float a, float b) {
    return (u32)f2bf(a) | ((u32)f2bf(b) << 16);
}
__device__ __forceinline__ void gload16(const u16* g, char* lds) {
    __builtin_amdgcn_global_load_lds((const AS1 u32*)g, (AS3 u32*)lds, 16, 0, 0);
}

// ---- core 128x128 GEMM tile, BK=32, 4 waves, global_load_lds staging -------
// LDS layout [128 rows][32 k] bf16 (64B rows), 16B-slot swizzle: LDS[r][slot]
// holds global slot (slot ^ ((r>>1)&3)). gload_lds dest linear; source lane
// address pre-swizzled; frag ds_read applies the same XOR.
__device__ __forceinline__ void gemm_core128(
    const u16* __restrict__ A1, int lda1, int acol, int K1,
    const u16* __restrict__ A2, int lda2,
    const u16* __restrict__ Wtg, int ldw, int n0,
    const float* __restrict__ bias, int addBias,
    float* __restrict__ Cf, u16* __restrict__ Cb, int ldc, int col0,
    int m0, int kbeg, int nk, u16* As, u16* Bs)
{
    const int t = threadIdx.x;
    const int lane = t & 63;
    const int wv = t >> 6;
    const int wr = (wv >> 1) << 6;
    const int wc = (wv & 1) << 6;
    const int lr = lane & 15;
    const int hi = lane >> 4;

    const int srow  = lane >> 2;                      // staging row within 16-row chunk
    const int scol8 = ((lane & 3) ^ ((lane >> 3) & 3)) * 8;  // pre-swizzled src slot

    const int lo0 = __builtin_amdgcn_readfirstlane(wv * 1024);
    const int lo1 = __builtin_amdgcn_readfirstlane(4096 + wv * 1024);

    const int fs = (hi ^ ((lr >> 1) & 3)) * 8;        // swizzled frag slot
    const u16* ard = As + (wr + lr) * 32 + fs;
    const u16* brd = Bs + (wc + lr) * 32 + fs;

    f32x4 acc[4][4];
    #pragma unroll
    for (int i = 0; i < 4; ++i)
        #pragma unroll
        for (int j = 0; j < 4; ++j)
            acc[i][j] = (f32x4){0.f, 0.f, 0.f, 0.f};

    for (int kt = 0; kt < nk; ++kt) {
        const int k0c = kbeg + (kt << 5);
        const u16* asrc; int alda; int ac;
        if (k0c < K1) { asrc = A1; alda = lda1; ac = acol + k0c; }
        else          { asrc = A2; alda = lda2; ac = k0c - K1; }

        gload16(asrc + (size_t)(m0 + wv * 16 + srow) * alda + ac + scol8, (char*)As + lo0);
        gload16(asrc + (size_t)(m0 + 64 + wv * 16 + srow) * alda + ac + scol8, (char*)As + lo1);
        gload16(Wtg + (size_t)(n0 + wv * 16 + srow) * ldw + k0c + scol8, (char*)Bs + lo0);
        gload16(Wtg + (size_t)(n0 + 64 + wv * 16 + srow) * ldw + k0c + scol8, (char*)Bs + lo1);

        __syncthreads();

        bf16x8 af[4], bfv[4];
        #pragma unroll
        for (int i = 0; i < 4; ++i) af[i]  = *(const bf16x8*)(ard + i * 512);
        #pragma unroll
        for (int j = 0; j < 4; ++j) bfv[j] = *(const bf16x8*)(brd + j * 512);
        #pragma unroll
        for (int i = 0; i < 4; ++i)
            #pragma unroll
            for (int j = 0; j < 4; ++j)
                acc[i][j] = __builtin_amdgcn_mfma_f32_16x16x32_bf16(af[i], bfv[j], acc[i][j], 0, 0, 0);

        __syncthreads();
    }

    const int cr = hi << 2;
    #pragma unroll
    for (int i = 0; i < 4; ++i) {
        const int row = m0 + wr + i * 16 + cr;
        #pragma unroll
        for (int j = 0; j < 4; ++j) {
            const int cc = col0 + wc + j * 16 + lr;
            const float bv = addBias ? bias[cc] : 0.f;
            #pragma unroll
            for (int r = 0; r < 4; ++r) {
                float v = acc[i][j][r] + bv;
                if (Cb) Cb[(size_t)(row + r) * ldc + cc] = f2bf(v);
                else    Cf[(size_t)(row + r) * ldc + cc] = v;
            }
        }
    }
}

// Blocked GEMM (hw0 / hw1 / gate): z = g*nSplit + s.
__global__ __launch_bounds__(256) void gemm_blk(
    const u16* __restrict__ A1, int lda1, int a1_goff, int K1,
    const u16* __restrict__ A2, int lda2,
    const u16* __restrict__ Wt, int Ktot, const float* __restrict__ bias,
    float* __restrict__ Cf, u16* __restrict__ Cb, int ldc, int Nb,
    int nSplit, int Kchunk, long pstride)
{
    __shared__ u16 As[4096], Bs[4096];
    const int z = blockIdx.z;
    const int g = z / nSplit;
    const int s = z - g * nSplit;
    const int n0 = blockIdx.x << 7;
    const int m0 = blockIdx.y << 7;
    const u16* Wtg = Wt + (size_t)g * Nb * Ktot;
    float* Cfs = Cf ? Cf + (size_t)s * pstride : nullptr;
    gemm_core128(A1, lda1, a1_goff * g, K1, A2, lda2,
                 Wtg, Ktot, n0, bias, s == 0,
                 Cfs, Cb, ldc, g * Nb + n0, m0, s * Kchunk, Kchunk >> 5, As, Bs);
}

// Table-driven branch GEMM (w0/w1/w2 with split-K), N=1024 for all entries.
struct BrEnt {
    const u16* A; const u16* Wt; const float* bias; float* Cp;
    int lda, ldw, kbeg, nk, addBias;
};
struct BrTab { BrEnt e[5]; };

__global__ __launch_bounds__(256) void gemm_tab(BrTab tab) {
    __shared__ u16 As[4096], Bs[4096];
    const BrEnt e = tab.e[blockIdx.z];
    const int n0 = blockIdx.x << 7;
    const int m0 = blockIdx.y << 7;
    gemm_core128(e.A, e.lda, 0, 1 << 30, nullptr, 0,
                 e.Wt, e.ldw, n0, e.bias, e.addBias,
                 e.Cp, nullptr, 3072, n0, m0, e.kbeg, e.nk, As, Bs);
}

// Sum S split partials + RMSNorm(gain) + SiLU -> bf16. grid (rows, nseg).
__global__ __launch_bounds__(256) void norm_silu(
    const float* __restrict__ in, int ldin, long pstride,
    int S0, int S1, int S2,
    const float* __restrict__ g0, const float* __restrict__ g1, const float* __restrict__ g2,
    u16* __restrict__ out, int ldout, int D)
{
    const int row = blockIdx.x, br = blockIdx.y;
    const float* gain = (br == 0) ? g0 : (br == 1) ? g1 : g2;
    const int S = (br == 0) ? S0 : (br == 1) ? S1 : S2;
    const float* ip = in + (size_t)row * ldin + (size_t)br * D;
    u16* op = out + (size_t)row * ldout + (size_t)br * D;
    const int t = threadIdx.x;
    const int nc = D >> 10;

    float4 cache[4];
    float ss = 0.f;
    #pragma unroll
    for (int c = 0; c < 4; ++c) if (c < nc) {
        int i = c * 1024 + t * 4;
        float4 v = *(const float4*)(ip + i);
        for (int s2 = 1; s2 < S; ++s2) {
            float4 w = *(const float4*)(ip + (size_t)s2 * pstride + i);
            v.x += w.x; v.y += w.y; v.z += w.z; v.w += w.w;
        }
        cache[c] = v;
        ss += v.x * v.x + v.y * v.y + v.z * v.z + v.w * v.w;
    }
    #pragma unroll
    for (int o = 32; o > 0; o >>= 1) ss += __shfl_down(ss, o, 64);
    __shared__ float sred[4];
    if ((t & 63) == 0) sred[t >> 6] = ss;
    __syncthreads();
    float tot = sred[0] + sred[1] + sred[2] + sred[3];
    float scale = rsqrtf(tot / (float)D + 1e-4f);

    #pragma unroll
    for (int c = 0; c < 4; ++c) if (c < nc) {
        int i = c * 1024 + t * 4;
        float4 v = cache[c];
        float4 gv = *(const float4*)(gain + i);
        float y; short4 h;
        y = v.x * scale * gv.x; h.x = (short)f2bf(y / (1.f + __expf(-y)));
        y = v.y * scale * gv.y; h.y = (short)f2bf(y / (1.f + __expf(-y)));
        y = v.z * scale * gv.z; h.z = (short)f2bf(y / (1.f + __expf(-y)));
        y = v.w * scale * gv.w; h.w = (short)f2bf(y / (1.f + __expf(-y)));
        *(short4*)(op + i) = h;
    }
}

// Convert deter/stoch to bf16; normalize+convert action. 8 elems/thread.
__global__ __launch_bounds__(256) void prep_cvt(
    const float* __restrict__ deter, const float* __restrict__ stoch,
    const float* __restrict__ act,
    u16* __restrict__ dbf, u16* __restrict__ sbf, u16* __restrict__ abf)
{
    const int i8 = (blockIdx.x * 256 + threadIdx.x) * 8;
    const float* src; u16* dst; int off; bool nrm = false;
    if (i8 < 4194304)                { src = deter; dst = dbf; off = i8; }
    else if (i8 < 4194304 + 1048576) { src = stoch; dst = sbf; off = i8 - 4194304; }
    else                             { src = act;   dst = abf; off = i8 - 5242880; nrm = true; }
    float4 a = *(const float4*)(src + off);
    float4 b = *(const float4*)(src + off + 4);
    if (nrm) {
        a.x /= fmaxf(fabsf(a.x), 1.f); a.y /= fmaxf(fabsf(a.y), 1.f);
        a.z /= fmaxf(fabsf(a.z), 1.f); a.w /= fmaxf(fabsf(a.w), 1.f);
        b.x /= fmaxf(fabsf(b.x), 1.f); b.y /= fmaxf(fabsf(b.y), 1.f);
        b.z /= fmaxf(fabsf(b.z), 1.f); b.w /= fmaxf(fabsf(b.w), 1.f);
    }
    int4 o;
    o.x = (int)pk2(a.x, a.y); o.y = (int)pk2(a.z, a.w);
    o.z = (int)pk2(b.x, b.y); o.w = (int)pk2(b.z, b.w);
    *(int4*)(dst + off) = o;
}

// Transpose+convert all weights: f32 [g][K][N] -> bf16 [g][N][K]. 64x64 tiles.
__global__ __launch_bounds__(256) void wtrans(
    const float* __restrict__ w0, const float* __restrict__ w1, const float* __restrict__ w2,
    const float* __restrict__ hw0, const float* __restrict__ hw1, const float* __restrict__ gw,
    u16* __restrict__ w0t, u16* __restrict__ w1t, u16* __restrict__ w2t,
    u16* __restrict__ hw0t, u16* __restrict__ hw1t, u16* __restrict__ gwt)
{
    __shared__ float Ls[64][68];
    const int bid = blockIdx.x;
    const float* src; u16* dst; int K, N, loc;
    if (bid < 1024)      { src = w0;  dst = w0t;  K = 4096; N = 1024; loc = bid; }
    else if (bid < 1280) { src = w1;  dst = w1t;  K = 1024; N = 1024; loc = bid - 1024; }
    else if (bid < 1312) { src = w2;  dst = w2t;  K = 128;  N = 1024; loc = bid - 1280; }
    else if (bid < 4896) { src = hw0; dst = hw0t; K = 3584; N = 512;  loc = bid - 1312; }
    else if (bid < 5408) { src = hw1; dst = hw1t; K = 512;  N = 512;  loc = bid - 4896; }
    else                 { src = gw;  dst = gwt;  K = 512;  N = 1536; loc = bid - 5408; }
    const int ntiles = N >> 6, ktiles = K >> 6, tpg = ktiles * ntiles;
    const int g = loc / tpg, rem = loc % tpg;
    const int kt = rem / ntiles, nt = rem % ntiles;
    const float* sp = src + ((size_t)g * K + kt * 64) * N + nt * 64;
    u16* dp = dst + ((size_t)g * N + nt * 64) * K + kt * 64;
    const int t = threadIdx.x;

    const int rr = t >> 4, cc = (t & 15) << 2;
    #pragma unroll
    for (int p = 0; p < 4; ++p)
        *(float4*)&Ls[rr + 16 * p][cc] = *(const float4*)(sp + (size_t)(rr + 16 * p) * N + cc);
    __syncthreads();

    const int n = t >> 2, kk = (t & 3) << 4;
    u32 wo[8];
    #pragma unroll
    for (int j = 0; j < 8; ++j)
        wo[j] = pk2(Ls[kk + 2 * j][n], Ls[kk + 2 * j + 1][n]);
    u16* o = dp + (size_t)n * K + kk;
    int4 q0; q0.x = (int)wo[0]; q0.y = (int)wo[1]; q0.z = (int)wo[2]; q0.w = (int)wo[3];
    int4 q1; q1.x = (int)wo[4]; q1.y = (int)wo[5]; q1.z = (int)wo[6]; q1.w = (int)wo[7];
    *(int4*)o = q0;
    *(int4*)(o + 8) = q1;
}

__device__ __forceinline__ float gru1(float r, float cc, float u, float d) {
    float reset = 1.f / (1.f + __expf(-r));
    float cand = tanhf(reset * cc);
    float upd = 1.f / (1.f + __expf(-(u - 1.f)));
    return upd * cand + (1.f - upd) * d;
}

__global__ __launch_bounds__(256) void gru_k(const u16* __restrict__ pre,
                                             const float* __restrict__ deter,
                                             float* __restrict__ out)
{
    int idx = (blockIdx.x * 256 + threadIdx.x) * 4;
    int b = idx >> 12;
    int c = idx & 4095;
    int g = c >> 9, ii = c & 511;
    const u16* p = pre + (size_t)b * 12288 + g * 1536 + ii;
    short4 pr = *(const short4*)p;
    short4 pc = *(const short4*)(p + 512);
    short4 pu = *(const short4*)(p + 1024);
    float4 dv = *(const float4*)(deter + idx);
    float4 o4;
    o4.x = gru1(bf2f((u16)pr.x), bf2f((u16)pc.x), bf2f((u16)pu.x), dv.x);
    o4.y = gru1(bf2f((u16)pr.y), bf2f((u16)pc.y), bf2f((u16)pu.y), dv.y);
    o4.z = gru1(bf2f((u16)pr.z), bf2f((u16)pc.z), bf2f((u16)pu.z), dv.z);
    o4.w = gru1(bf2f((u16)pr.w), bf2f((u16)pc.w), bf2f((u16)pu.w), dv.w);
    *(float4*)(out + idx) = o4;
}

extern "C" void kernel_launch(void* const* d_in, const int* in_sizes, int n_in,
                              void* d_out, int out_size, void* d_ws, size_t ws_size,
                              hipStream_t stream)
{
    (void)in_sizes; (void)n_in; (void)out_size; (void)ws_size;
    const float* stoch  = (const float*)d_in[0];
    const float* deter  = (const float*)d_in[1];
    const float* action = (const float*)d_in[2];
    const float* w0 = (const float*)d_in[3];
    const float* b0 = (const float*)d_in[4];
    const float* g0 = (const float*)d_in[5];
    const float* w1 = (const float*)d_in[6];
    const float* b1 = (const float*)d_in[7];
    const float* g1 = (const float*)d_in[8];
    const float* w2 = (const float*)d_in[9];
    const float* b2 = (const float*)d_in[10];
    const float* g2 = (const float*)d_in[11];
    const float* hw0 = (const float*)d_in[12];
    const float* hb0 = (const float*)d_in[13];
    const float* hg0 = (const float*)d_in[14];
    const float* hw1 = (const float*)d_in[15];
    const float* hb1 = (const float*)d_in[16];
    const float* hg1 = (const float*)d_in[17];
    const float* gw  = (const float*)d_in[18];
    const float* gb  = (const float*)d_in[19];
    float* out = (float*)d_out;

    // workspace layout (~110.5 MB)
    char* ws = (char*)d_ws;
    float* part = (float*)ws;                              // 8,388,608 f32 (33.5MB)
    u16* wreg = (u16*)(ws + 33554432);                     // 28,442,624 bf16 (56.9MB)
    u16* w0t  = wreg;
    u16* w1t  = w0t + 4194304;
    u16* w2t  = w1t + 1048576;
    u16* hw0t = w2t + 131072;
    u16* hw1t = hw0t + 14680064;
    u16* gwt  = hw1t + 2097152;
    u16* dbf  = (u16*)(ws + 33554432 + 56885248);          // 4,194,304
    u16* sbf  = dbf + 4194304;                             // 1,048,576
    u16* abf  = sbf + 1048576;                             // 131,072
    u16* xbuf = abf + 131072;                              // 1024x3072
    u16* hbuf = xbuf + 3145728;                            // 1024x4096
    u16* gpre = (u16*)part;                                // gate pre reuses part

    const long PS_BR = 3145728;   // 1024*3072
    const long PS_H  = 4194304;   // 1024*4096
    dim3 blk(256);

    prep_cvt<<<2624, blk, 0, stream>>>(deter, stoch, action, dbf, sbf, abf);
    wtrans<<<6944, blk, 0, stream>>>(w0, w1, w2, hw0, hw1, gw,
                                     w0t, w1t, w2t, hw0t, hw1t, gwt);

    BrTab tab;
    tab.e[0] = { dbf, w0t, b0, part,                 4096, 4096, 0,    64, 1 };
    tab.e[1] = { dbf, w0t, b0, part + PS_BR,         4096, 4096, 2048, 64, 0 };
    tab.e[2] = { sbf, w1t, b1, part + 1024,          1024, 1024, 0,    16, 1 };
    tab.e[3] = { sbf, w1t, b1, part + PS_BR + 1024,  1024, 1024, 512,  16, 0 };
    tab.e[4] = { abf, w2t, b2, part + 2048,          128,  128,  0,    4,  1 };
    gemm_tab<<<dim3(8, 8, 5), blk, 0, stream>>>(tab);

    norm_silu<<<dim3(1024, 3), blk, 0, stream>>>(part, 3072, PS_BR, 2, 2, 1,
                                                 g0, g1, g2, xbuf, 3072, 1024);

    // hidden layer 0: A = [deter_g | x], K=3584, split-K S=2
    gemm_blk<<<dim3(4, 8, 16), blk, 0, stream>>>(dbf, 4096, 512, 512, xbuf, 3072,
        hw0t, 3584, hb0, part, nullptr, 4096, 512, 2, 1792, PS_H);
    norm_silu<<<dim3(1024, 1), blk, 0, stream>>>(part, 4096, PS_H, 2, 2, 2,
                                                 hg0, hg0, hg0, hbuf, 4096, 4096);

    // hidden layer 1: block-diagonal K=512, S=2
    gemm_blk<<<dim3(4, 8, 16), blk, 0, stream>>>(hbuf, 4096, 512, 512, nullptr, 0,
        hw1t, 512, hb1, part, nullptr, 4096, 512, 2, 256, PS_H);
    norm_silu<<<dim3(1024, 1), blk, 0, stream>>>(part, 4096, PS_H, 2, 2, 2,
                                                 hg1, hg1, hg1, hbuf, 4096, 4096);

    // gate: block-diagonal K=512 -> bf16 [1024][12288]
    gemm_blk<<<dim3(12, 8, 8), blk, 0, stream>>>(hbuf, 4096, 512, 512, nullptr, 0,
        gwt, 512, gb, nullptr, gpre, 12288, 1536, 1, 512, 0);

    gru_k<<<4096, blk, 0, stream>>>(gpre, deter, out);
}

// Round 4
// 345.079 us; speedup vs baseline: 1.8355x; 1.0937x over previous
//
#include <hip/hip_runtime.h>
#include <hip/hip_bf16.h>

// Deter GRU cell on MI355X. bf16 MFMA GEMMs with global_load_lds staging,
// double-buffered LDS (one barrier per K-step), split-K bf16 partials summed
// in the fused RMSNorm consumers. Weights transposed+converted once per call.

typedef unsigned short u16;
typedef unsigned int u32;
typedef __attribute__((ext_vector_type(8))) __bf16 bf16x8;
typedef __attribute__((ext_vector_type(4))) float f32x4;

#define AS3 __attribute__((address_space(3)))
#define AS1 __attribute__((address_space(1)))

__device__ __forceinline__ u16 f2bf(float f) {
    union { float f; u32 u; } a; a.f = f;
    u32 r = a.u + 0x7FFFu + ((a.u >> 16) & 1u);
    return (u16)(r >> 16);
}
__device__ __forceinline__ float bf2f(u16 h) {
    union { u32 u; float f; } c; c.u = ((u32)h) << 16; return c.f;
}
__device__ __forceinline__ u32 pk2(float a, float b) {
    return (u32)f2bf(a) | ((u32)f2bf(b) << 16);
}
__device__ __forceinline__ void gload16(const u16* g, char* lds) {
    __builtin_amdgcn_global_load_lds((const AS1 u32*)g, (AS3 u32*)lds, 16, 0, 0);
}

// ---- core 128x128 GEMM tile, BK=32, 4 waves, gload_lds, 2-phase dbuf -------
// LDS [128][32] bf16 per buffer; 16B-slot swizzle: LDS[r][s] holds global slot
// s ^ ((r>>1)&3); gload_lds dest linear, source pre-swizzled, frag read XORed.
__device__ __forceinline__ void gemm_core128(
    const u16* __restrict__ A1, int lda1, int acol, int K1,
    const u16* __restrict__ A2, int lda2,
    const u16* __restrict__ Wtg, int ldw, int n0,
    const float* __restrict__ bias, int addBias,
    u16* __restrict__ Cb, int ldc, int col0,
    int m0, int kbeg, int nk, u16* As, u16* Bs)
{
    const int t = threadIdx.x;
    const int lane = t & 63;
    const int wv = t >> 6;
    const int wr = (wv >> 1) << 6;
    const int wc = (wv & 1) << 6;
    const int lr = lane & 15;
    const int hi = lane >> 4;

    const int srow  = lane >> 2;
    const int scol8 = ((lane & 3) ^ ((lane >> 3) & 3)) * 8;
    const int fs = (hi ^ ((lr >> 1) & 3)) * 8;

    f32x4 acc[4][4];
    #pragma unroll
    for (int i = 0; i < 4; ++i)
        #pragma unroll
        for (int j = 0; j < 4; ++j)
            acc[i][j] = (f32x4){0.f, 0.f, 0.f, 0.f};

    auto stage = [&](int k0c, int bufo) {
        const u16* asrc; int alda; int ac;
        if (k0c < K1) { asrc = A1; alda = lda1; ac = acol + k0c; }
        else          { asrc = A2; alda = lda2; ac = k0c - K1; }
        const int lo0 = __builtin_amdgcn_readfirstlane(bufo + wv * 1024);
        const int lo1 = __builtin_amdgcn_readfirstlane(bufo + 4096 + wv * 1024);
        gload16(asrc + (size_t)(m0 + wv * 16 + srow) * alda + ac + scol8, (char*)As + lo0);
        gload16(asrc + (size_t)(m0 + 64 + wv * 16 + srow) * alda + ac + scol8, (char*)As + lo1);
        gload16(Wtg + (size_t)(n0 + wv * 16 + srow) * ldw + k0c + scol8, (char*)Bs + lo0);
        gload16(Wtg + (size_t)(n0 + 64 + wv * 16 + srow) * ldw + k0c + scol8, (char*)Bs + lo1);
    };

    stage(kbeg, 0);
    __syncthreads();

    for (int kt = 0; kt < nk; ++kt) {
        const int bo = (kt & 1) << 13;                 // byte offset of current buf
        if (kt + 1 < nk) stage(kbeg + ((kt + 1) << 5), 8192 - bo);

        const u16* ard = As + ((kt & 1) << 12) + (wr + lr) * 32 + fs;
        const u16* brd = Bs + ((kt & 1) << 12) + (wc + lr) * 32 + fs;
        bf16x8 af[4], bfv[4];
        #pragma unroll
        for (int i = 0; i < 4; ++i) af[i]  = *(const bf16x8*)(ard + i * 512);
        #pragma unroll
        for (int j = 0; j < 4; ++j) bfv[j] = *(const bf16x8*)(brd + j * 512);
        #pragma unroll
        for (int i = 0; i < 4; ++i)
            #pragma unroll
            for (int j = 0; j < 4; ++j)
                acc[i][j] = __builtin_amdgcn_mfma_f32_16x16x32_bf16(af[i], bfv[j], acc[i][j], 0, 0, 0);

        __syncthreads();   // drains vmcnt: next-tile stage landed; all reads of bo done
    }

    const int cr = hi << 2;
    #pragma unroll
    for (int i = 0; i < 4; ++i) {
        const int row = m0 + wr + i * 16 + cr;
        #pragma unroll
        for (int j = 0; j < 4; ++j) {
            const int cc = col0 + wc + j * 16 + lr;
            const float bv = addBias ? bias[cc] : 0.f;
            #pragma unroll
            for (int r = 0; r < 4; ++r)
                Cb[(size_t)(row + r) * ldc + cc] = f2bf(acc[i][j][r] + bv);
        }
    }
}

// Blocked GEMM (hw0/hw1/gate): z = g*nSplit + s.
__global__ __launch_bounds__(256) void gemm_blk(
    const u16* __restrict__ A1, int lda1, int a1_goff, int K1,
    const u16* __restrict__ A2, int lda2,
    const u16* __restrict__ Wt, int Ktot, const float* __restrict__ bias,
    u16* __restrict__ Cb, int ldc, int Nb,
    int nSplit, int Kchunk, long pstride)
{
    __shared__ u16 As[8192], Bs[8192];
    const int z = blockIdx.z;
    const int g = z / nSplit;
    const int s = z - g * nSplit;
    const int n0 = blockIdx.x << 7;
    const int m0 = blockIdx.y << 7;
    const u16* Wtg = Wt + (size_t)g * Nb * Ktot;
    gemm_core128(A1, lda1, a1_goff * g, K1, A2, lda2,
                 Wtg, Ktot, n0, bias, s == 0,
                 Cb + (size_t)s * pstride, ldc, g * Nb + n0,
                 m0, s * Kchunk, Kchunk >> 5, As, Bs);
}

// Table-driven branch GEMMs (w0 S=8, w1 S=2, w2 S=1), all N=1024.
struct BrEnt {
    const u16* A; const u16* Wt; const float* bias; u16* Cb;
    int lda, ldw, kbeg, nk, addBias;
};
struct BrTab { BrEnt e[11]; };

__global__ __launch_bounds__(256) void gemm_tab(BrTab tab) {
    __shared__ u16 As[8192], Bs[8192];
    const BrEnt e = tab.e[blockIdx.z];
    const int n0 = blockIdx.x << 7;
    const int m0 = blockIdx.y << 7;
    gemm_core128(e.A, e.lda, 0, 1 << 30, nullptr, 0,
                 e.Wt, e.ldw, n0, e.bias, e.addBias,
                 e.Cb, 1024, n0, m0, e.kbeg, e.nk, As, Bs);
}

// Sum S bf16 partials + RMSNorm(gain) + SiLU -> bf16. grid (rows, nseg).
struct Seg { const u16* in; long pstride; int S; const float* gain; int ld; };
struct NormArgs { Seg s[3]; };

__global__ __launch_bounds__(256) void norm_silu(NormArgs na, u16* __restrict__ out,
                                                 int ldout, int D)
{
    const int row = blockIdx.x, br = blockIdx.y;
    const Seg sg = na.s[br];
    const u16* ip = sg.in + (size_t)row * sg.ld;
    u16* op = out + (size_t)row * ldout + (size_t)br * D;
    const int t = threadIdx.x;
    const int nc = D >> 10;

    float4 cache[4];
    float ss = 0.f;
    #pragma unroll
    for (int c = 0; c < 4; ++c) if (c < nc) {
        int i = c * 1024 + t * 4;
        float4 v = {0.f, 0.f, 0.f, 0.f};
        for (int s2 = 0; s2 < sg.S; ++s2) {
            short4 h = *(const short4*)(ip + (size_t)s2 * sg.pstride + i);
            v.x += bf2f((u16)h.x); v.y += bf2f((u16)h.y);
            v.z += bf2f((u16)h.z); v.w += bf2f((u16)h.w);
        }
        cache[c] = v;
        ss += v.x * v.x + v.y * v.y + v.z * v.z + v.w * v.w;
    }
    #pragma unroll
    for (int o = 32; o > 0; o >>= 1) ss += __shfl_down(ss, o, 64);
    __shared__ float sred[4];
    if ((t & 63) == 0) sred[t >> 6] = ss;
    __syncthreads();
    float tot = sred[0] + sred[1] + sred[2] + sred[3];
    float scale = rsqrtf(tot / (float)D + 1e-4f);

    #pragma unroll
    for (int c = 0; c < 4; ++c) if (c < nc) {
        int i = c * 1024 + t * 4;
        float4 v = cache[c];
        float4 gv = *(const float4*)(sg.gain + i);
        float y; short4 h;
        y = v.x * scale * gv.x; h.x = (short)f2bf(y / (1.f + __expf(-y)));
        y = v.y * scale * gv.y; h.y = (short)f2bf(y / (1.f + __expf(-y)));
        y = v.z * scale * gv.z; h.z = (short)f2bf(y / (1.f + __expf(-y)));
        y = v.w * scale * gv.w; h.w = (short)f2bf(y / (1.f + __expf(-y)));
        *(short4*)(op + i) = h;
    }
}

// Merged: weight transpose+convert (bid<6944) and activation convert (rest).
__global__ __launch_bounds__(256) void prep_all(
    const float* __restrict__ w0, const float* __restrict__ w1, const float* __restrict__ w2,
    const float* __restrict__ hw0, const float* __restrict__ hw1, const float* __restrict__ gw,
    u16* __restrict__ w0t, u16* __restrict__ w1t, u16* __restrict__ w2t,
    u16* __restrict__ hw0t, u16* __restrict__ hw1t, u16* __restrict__ gwt,
    const float* __restrict__ deter, const float* __restrict__ stoch,
    const float* __restrict__ act,
    u16* __restrict__ dbf, u16* __restrict__ sbf, u16* __restrict__ abf)
{
    __shared__ float Ls[64][68];
    const int bid = blockIdx.x;
    const int t = threadIdx.x;
    if (bid < 6944) {
        const float* src; u16* dst; int K, N, loc;
        if (bid < 1024)      { src = w0;  dst = w0t;  K = 4096; N = 1024; loc = bid; }
        else if (bid < 1280) { src = w1;  dst = w1t;  K = 1024; N = 1024; loc = bid - 1024; }
        else if (bid < 1312) { src = w2;  dst = w2t;  K = 128;  N = 1024; loc = bid - 1280; }
        else if (bid < 4896) { src = hw0; dst = hw0t; K = 3584; N = 512;  loc = bid - 1312; }
        else if (bid < 5408) { src = hw1; dst = hw1t; K = 512;  N = 512;  loc = bid - 4896; }
        else                 { src = gw;  dst = gwt;  K = 512;  N = 1536; loc = bid - 5408; }
        const int ntiles = N >> 6, ktiles = K >> 6, tpg = ktiles * ntiles;
        const int g = loc / tpg, rem = loc % tpg;
        const int kt = rem / ntiles, nt = rem % ntiles;
        const float* sp = src + ((size_t)g * K + kt * 64) * N + nt * 64;
        u16* dp = dst + ((size_t)g * N + nt * 64) * K + kt * 64;

        const int rr = t >> 4, cc = (t & 15) << 2;
        #pragma unroll
        for (int p = 0; p < 4; ++p)
            *(float4*)&Ls[rr + 16 * p][cc] = *(const float4*)(sp + (size_t)(rr + 16 * p) * N + cc);
        __syncthreads();

        const int n = t >> 2, kk = (t & 3) << 4;
        u32 wo[8];
        #pragma unroll
        for (int j = 0; j < 8; ++j)
            wo[j] = pk2(Ls[kk + 2 * j][n], Ls[kk + 2 * j + 1][n]);
        u16* o = dp + (size_t)n * K + kk;
        int4 q0; q0.x = (int)wo[0]; q0.y = (int)wo[1]; q0.z = (int)wo[2]; q0.w = (int)wo[3];
        int4 q1; q1.x = (int)wo[4]; q1.y = (int)wo[5]; q1.z = (int)wo[6]; q1.w = (int)wo[7];
        *(int4*)o = q0;
        *(int4*)(o + 8) = q1;
    } else {
        const int i8 = ((bid - 6944) * 256 + t) * 8;
        const float* src; u16* dst; int off; bool nrm = false;
        if (i8 < 4194304)      { src = deter; dst = dbf; off = i8; }
        else if (i8 < 5242880) { src = stoch; dst = sbf; off = i8 - 4194304; }
        else                   { src = act;   dst = abf; off = i8 - 5242880; nrm = true; }
        float4 a = *(const float4*)(src + off);
        float4 b = *(const float4*)(src + off + 4);
        if (nrm) {
            a.x /= fmaxf(fabsf(a.x), 1.f); a.y /= fmaxf(fabsf(a.y), 1.f);
            a.z /= fmaxf(fabsf(a.z), 1.f); a.w /= fmaxf(fabsf(a.w), 1.f);
            b.x /= fmaxf(fabsf(b.x), 1.f); b.y /= fmaxf(fabsf(b.y), 1.f);
            b.z /= fmaxf(fabsf(b.z), 1.f); b.w /= fmaxf(fabsf(b.w), 1.f);
        }
        int4 o;
        o.x = (int)pk2(a.x, a.y); o.y = (int)pk2(a.z, a.w);
        o.z = (int)pk2(b.x, b.y); o.w = (int)pk2(b.z, b.w);
        *(int4*)(dst + off) = o;
    }
}

__device__ __forceinline__ float gru1(float r, float cc, float u, float d) {
    float reset = 1.f / (1.f + __expf(-r));
    float cand = tanhf(reset * cc);
    float upd = 1.f / (1.f + __expf(-(u - 1.f)));
    return upd * cand + (1.f - upd) * d;
}

__global__ __launch_bounds__(256) void gru_k(const u16* __restrict__ pre,
                                             const float* __restrict__ deter,
                                             float* __restrict__ out)
{
    int idx = (blockIdx.x * 256 + threadIdx.x) * 4;
    int b = idx >> 12;
    int c = idx & 4095;
    int g = c >> 9, ii = c & 511;
    const u16* p = pre + (size_t)b * 12288 + g * 1536 + ii;
    short4 pr = *(const short4*)p;
    short4 pc = *(const short4*)(p + 512);
    short4 pu = *(const short4*)(p + 1024);
    float4 dv = *(const float4*)(deter + idx);
    float4 o4;
    o4.x = gru1(bf2f((u16)pr.x), bf2f((u16)pc.x), bf2f((u16)pu.x), dv.x);
    o4.y = gru1(bf2f((u16)pr.y), bf2f((u16)pc.y), bf2f((u16)pu.y), dv.y);
    o4.z = gru1(bf2f((u16)pr.z), bf2f((u16)pc.z), bf2f((u16)pu.z), dv.z);
    o4.w = gru1(bf2f((u16)pr.w), bf2f((u16)pc.w), bf2f((u16)pu.w), dv.w);
    *(float4*)(out + idx) = o4;
}

extern "C" void kernel_launch(void* const* d_in, const int* in_sizes, int n_in,
                              void* d_out, int out_size, void* d_ws, size_t ws_size,
                              hipStream_t stream)
{
    (void)in_sizes; (void)n_in; (void)out_size; (void)ws_size;
    const float* stoch  = (const float*)d_in[0];
    const float* deter  = (const float*)d_in[1];
    const float* action = (const float*)d_in[2];
    const float* w0 = (const float*)d_in[3];
    const float* b0 = (const float*)d_in[4];
    const float* g0 = (const float*)d_in[5];
    const float* w1 = (const float*)d_in[6];
    const float* b1 = (const float*)d_in[7];
    const float* g1 = (const float*)d_in[8];
    const float* w2 = (const float*)d_in[9];
    const float* b2 = (const float*)d_in[10];
    const float* g2 = (const float*)d_in[11];
    const float* hw0 = (const float*)d_in[12];
    const float* hb0 = (const float*)d_in[13];
    const float* hg0 = (const float*)d_in[14];
    const float* hw1 = (const float*)d_in[15];
    const float* hb1 = (const float*)d_in[16];
    const float* hg1 = (const float*)d_in[17];
    const float* gw  = (const float*)d_in[18];
    const float* gb  = (const float*)d_in[19];
    float* out = (float*)d_out;

    // workspace (u16 units): scratch 16,777,216 | weights 28,442,624 | acts 12,713,984
    // total 57,933,824 u16 = 110.5 MB
    u16* scratch = (u16*)d_ws;
    u16* wreg = scratch + 16777216;
    u16* w0t  = wreg;
    u16* w1t  = w0t + 4194304;
    u16* w2t  = w1t + 1048576;
    u16* hw0t = w2t + 131072;
    u16* hw1t = hw0t + 14680064;
    u16* gwt  = hw1t + 2097152;
    u16* dbf  = wreg + 28442624;
    u16* sbf  = dbf + 4194304;
    u16* abf  = sbf + 1048576;
    u16* xbuf = abf + 131072;
    u16* hbuf = xbuf + 3145728;
    // scratch aliases (sequential lifetimes):
    u16* bp0 = scratch;               // 8 x [1024][1024]
    u16* bp1 = scratch + 8388608;     // 2 x [1024][1024]
    u16* bp2 = scratch + 10485760;    // 1 x [1024][1024]
    u16* hpart = scratch;             // up to 4 x [1024][4096]
    u16* gpre  = scratch;             // [1024][12288]

    dim3 blk(256);

    prep_all<<<9568, blk, 0, stream>>>(w0, w1, w2, hw0, hw1, gw,
                                       w0t, w1t, w2t, hw0t, hw1t, gwt,
                                       deter, stoch, action, dbf, sbf, abf);

    BrTab tab;
    for (int s = 0; s < 8; ++s)
        tab.e[s]   = { dbf, w0t, b0, bp0 + (size_t)s * 1048576, 4096, 4096, 512 * s, 16, s == 0 };
    for (int s = 0; s < 2; ++s)
        tab.e[8+s] = { sbf, w1t, b1, bp1 + (size_t)s * 1048576, 1024, 1024, 512 * s, 16, s == 0 };
    tab.e[10]      = { abf, w2t, b2, bp2,                       128,  128,  0,       4,  1 };
    gemm_tab<<<dim3(8, 8, 11), blk, 0, stream>>>(tab);

    NormArgs nb;
    nb.s[0] = { bp0, 1048576, 8, g0, 1024 };
    nb.s[1] = { bp1, 1048576, 2, g1, 1024 };
    nb.s[2] = { bp2, 0,       1, g2, 1024 };
    norm_silu<<<dim3(1024, 3), blk, 0, stream>>>(nb, xbuf, 3072, 1024);

    // hidden layer 0: A = [deter_g | x], K=3584, S=4 (Kchunk 896)
    gemm_blk<<<dim3(4, 8, 32), blk, 0, stream>>>(dbf, 4096, 512, 512, xbuf, 3072,
        hw0t, 3584, hb0, hpart, 4096, 512, 4, 896, 4194304);
    NormArgs nh0; nh0.s[0] = nh0.s[1] = nh0.s[2] = { hpart, 4194304, 4, hg0, 4096 };
    norm_silu<<<dim3(1024, 1), blk, 0, stream>>>(nh0, hbuf, 4096, 4096);

    // hidden layer 1: block-diagonal K=512, S=2 (Kchunk 256)
    gemm_blk<<<dim3(4, 8, 16), blk, 0, stream>>>(hbuf, 4096, 512, 512, nullptr, 0,
        hw1t, 512, hb1, hpart, 4096, 512, 2, 256, 4194304);
    NormArgs nh1; nh1.s[0] = nh1.s[1] = nh1.s[2] = { hpart, 4194304, 2, hg1, 4096 };
    norm_silu<<<dim3(1024, 1), blk, 0, stream>>>(nh1, hbuf, 4096, 4096);

    // gate: block-diagonal K=512 -> bf16 [1024][12288]
    gemm_blk<<<dim3(12, 8, 8), blk, 0, stream>>>(hbuf, 4096, 512, 512, nullptr, 0,
        gwt, 512, gb, gpre, 12288, 1536, 1, 512, 0);

    gru_k<<<4096, blk, 0, stream>>>(gpre, deter, out);
}